// Round 5
// baseline (113.406 us; speedup 1.0000x reference)
//
#include <hip/hip_runtime.h>

#define HC 256
#define WC 256
#define CC 96
#define BB 4
#define OH 258
#define OW 258
#define PLANE 65536          // HC*WC
#define TOX 24               // out cols per tile (mult of 4)
#define TOY 6                // out rows per tile
#define RXC 32               // r-tile cols (8 quads)
#define RYC 8                // r-tile rows
#define NTX 11               // ceil(258/24)
#define NTY 43               // 258/6
#define CG 24                // channels per group (4 groups = 4 waves per block)

// out[b,d(tj,ti),y,x] = (1/864) * sum_{a,b2 in [0,3)} r(y-2+a, x-2+b2; tj,ti)
// r(h,w; tj,ti) = sum_c x1[b,c,h,w] * x2[b,c,h+tj-1,w+ti-1]  (OOB -> 0; d = tj*3+ti)

__device__ __forceinline__ float4 ld4(const float* p) {
    return *reinterpret_cast<const float4*>(p);
}

// a = x1 quad; window W[0..5] = x2 cols w-1..w+4 of row h+tj-1.
// px i (i=0..3) with shift ti uses W[i+ti].
#define FMA3(d0, L, R, e)                                                                  \
    do {                                                                                   \
        const float W0 = (L).w, W1 = (R).x, W2 = (R).y, W3 = (R).z, W4 = (R).w, W5 = (e);  \
        acc[d0].x = fmaf(a.x, W0, acc[d0].x);                                              \
        acc[d0].y = fmaf(a.y, W1, acc[d0].y);                                              \
        acc[d0].z = fmaf(a.z, W2, acc[d0].z);                                              \
        acc[d0].w = fmaf(a.w, W3, acc[d0].w);                                              \
        acc[d0+1].x = fmaf(a.x, W1, acc[d0+1].x);                                          \
        acc[d0+1].y = fmaf(a.y, W2, acc[d0+1].y);                                          \
        acc[d0+1].z = fmaf(a.z, W3, acc[d0+1].z);                                          \
        acc[d0+1].w = fmaf(a.w, W4, acc[d0+1].w);                                          \
        acc[d0+2].x = fmaf(a.x, W2, acc[d0+2].x);                                          \
        acc[d0+2].y = fmaf(a.y, W3, acc[d0+2].y);                                          \
        acc[d0+2].z = fmaf(a.z, W4, acc[d0+2].z);                                          \
        acc[d0+2].w = fmaf(a.w, W5, acc[d0+2].w);                                          \
    } while (0)

__global__ __launch_bounds__(256) void corr2d_kernel(
    const float* __restrict__ x1, const float* __restrict__ x2,
    float* __restrict__ out)
{
    const int tid  = threadIdx.x;
    const int g    = tid >> 6;       // channel group == wave id (0..3)
    const int lane = tid & 63;
    const int tx   = lane & 7;       // quad-col (cols 4*tx .. 4*tx+3 of r-tile)
    const int row  = lane >> 3;      // r-row within tile (0..7)

    const int bx = blockIdx.x, by = blockIdx.y, b = blockIdx.z;
    const int rs  = TOX * bx - 4;    // r-tile col start (global; == 0 mod 4)
    const int rsy = TOY * by - 2;    // r-tile row start
    const int w = rs + 4 * tx;       // this thread's quad start col
    const int h = rsy + row;         // this thread's r row

    const float* x1b = x1 + (size_t)(b * CC + g * CG) * PLANE;
    const float* x2b = x2 + (size_t)(b * CC + g * CG) * PLANE;

    float4 acc[9];
#pragma unroll
    for (int d = 0; d < 9; ++d) acc[d] = make_float4(0.f, 0.f, 0.f, 0.f);

    const int lp1 = (lane + 1) & 63; // shfl source (tx+1 same row; tx==7 wrap garbage
                                     // lands in unused r-cols 28..31: used rc <= TOX+3=27)

    const bool interior = (bx >= 1) && (bx <= 9) && (by >= 1) && (by <= 41);

    if (interior) {
        const float* q1 = x1b + h * WC + w;
        const float* q2 = x2b + h * WC + (w - 4);
#pragma unroll 2
        for (int c = 0; c < CG; ++c) {
            const float4 a  = ld4(q1);
            const float4 L0 = ld4(q2 - WC), R0 = ld4(q2 - WC + 4);
            const float4 L1 = ld4(q2),      R1 = ld4(q2 + 4);
            const float4 L2 = ld4(q2 + WC), R2 = ld4(q2 + WC + 4);
            const float e0 = __shfl(R0.x, lp1);
            const float e1 = __shfl(R1.x, lp1);
            const float e2 = __shfl(R2.x, lp1);
            FMA3(0, L0, R0, e0);
            FMA3(3, L1, R1, e1);
            FMA3(6, L2, R2, e2);
            q1 += PLANE; q2 += PLANE;
        }
    } else {
        // channel-invariant clamped offsets + full-vector validity masks.
        // All loads are 4-aligned and 4-wide, so each is fully in-image or fully out.
        bool hv[3]; int hro[3];
#pragma unroll
        for (int t = 0; t < 3; ++t) {
            const int hr = h - 1 + t;
            hv[t] = ((unsigned)hr < (unsigned)HC);
            const int hc = hr < 0 ? 0 : (hr > HC - 1 ? HC - 1 : hr);
            hro[t] = hc * WC;
        }
        const int wl = w - 4;
        const bool cvL = ((unsigned)wl <= (unsigned)(WC - 4));
        const bool cvR = ((unsigned)w  <= (unsigned)(WC - 4));
        const int  cL = wl < 0 ? 0 : (wl > WC - 4 ? WC - 4 : wl);
        const int  cR = w  < 0 ? 0 : (w  > WC - 4 ? WC - 4 : w);
        const bool mA = hv[1] && cvR;
        const int  offA = hro[1] + cR;

        const float* q1 = x1b;
        const float* q2 = x2b;
        for (int c = 0; c < CG; ++c) {
            float4 a = ld4(q1 + offA);
            if (!mA) a = make_float4(0.f, 0.f, 0.f, 0.f);
            float4 Ls[3], Rs[3];
#pragma unroll
            for (int t = 0; t < 3; ++t) {
                float4 L = ld4(q2 + hro[t] + cL);
                float4 R = ld4(q2 + hro[t] + cR);
                if (!(hv[t] && cvL)) L = make_float4(0.f, 0.f, 0.f, 0.f);
                if (!(hv[t] && cvR)) R = make_float4(0.f, 0.f, 0.f, 0.f);
                Ls[t] = L; Rs[t] = R;
            }
            const float e0 = __shfl(Rs[0].x, lp1);
            const float e1 = __shfl(Rs[1].x, lp1);
            const float e2 = __shfl(Rs[2].x, lp1);
            FMA3(0, Ls[0], Rs[0], e0);
            FMA3(3, Ls[1], Rs[1], e1);
            FMA3(6, Ls[2], Rs[2], e2);
            q1 += PLANE; q2 += PLANE;
        }
    }

    // 4-group reduction, 2 rounds over 2 LDS buffers (18.4 KB total)
    __shared__ __align__(16) float buf[2][9][RYC][RXC];

#define WRITE_BUF(i)                                                        \
    do {                                                                    \
        _Pragma("unroll")                                                   \
        for (int d = 0; d < 9; ++d)                                         \
            *reinterpret_cast<float4*>(&buf[i][d][row][4 * tx]) = acc[d];   \
    } while (0)
#define ADD_BUF(i)                                                          \
    do {                                                                    \
        _Pragma("unroll")                                                   \
        for (int d = 0; d < 9; ++d) {                                       \
            float4 v = *reinterpret_cast<float4*>(&buf[i][d][row][4 * tx]); \
            acc[d].x += v.x; acc[d].y += v.y;                               \
            acc[d].z += v.z; acc[d].w += v.w;                               \
        }                                                                   \
    } while (0)

    if (g == 1) WRITE_BUF(0);
    if (g == 3) WRITE_BUF(1);
    __syncthreads();
    if (g == 0) ADD_BUF(0);
    if (g == 2) ADD_BUF(1);
    __syncthreads();
    if (g == 2) WRITE_BUF(0);
    __syncthreads();
    if (g == 0) { ADD_BUF(0); WRITE_BUF(0); }
    __syncthreads();

    // 3x3 box over final r in buf[0] -> out tile (9 d x TOY x TOX values)
    const int x0 = TOX * bx, y0 = TOY * by;
    for (int j = tid; j < 9 * TOY * TOX; j += 256) {
        const int d  = j / (TOY * TOX);
        const int r2 = j - d * (TOY * TOX);
        const int oy = r2 / TOX;
        const int ox = r2 - oy * TOX;
        const int x = x0 + ox;
        if (x < OW) {
            float s = 0.f;
#pragma unroll
            for (int a2 = 0; a2 < 3; ++a2)
#pragma unroll
                for (int b2 = 0; b2 < 3; ++b2)
                    s += buf[0][d][oy + a2][ox + 2 + b2];
            out[((size_t)(b * 9 + d) * OH + (y0 + oy)) * OW + x] = s * (1.0f / 864.0f);
        }
    }
}

extern "C" void kernel_launch(void* const* d_in, const int* in_sizes, int n_in,
                              void* d_out, int out_size, void* d_ws, size_t ws_size,
                              hipStream_t stream) {
    const float* x1 = (const float*)d_in[0];
    const float* x2 = (const float*)d_in[1];
    float* out = (float*)d_out;
    dim3 grid(NTX, NTY, BB);
    dim3 block(256);
    hipLaunchKernelGGL(corr2d_kernel, grid, block, 0, stream, x1, x2, out);
}